// Round 5
// baseline (6525.450 us; speedup 1.0000x reference)
//
#include <hip/hip_runtime.h>
#include <math.h>

#define B 64
#define N 196
#define E 2048
#define D 512
#define AA 512
#define EM 512
#define V 10000
#define TSTEPS 20
#define XC 3072          // xcat: [inp(512) | awe(2048) | h(512)] contiguous
#define HOFF 2560        // h slot offset in xcat
#define AGW 2560         // ag row: [att2(512) | gate(2048)]
#define AGS 4            // split-K slices for att2|gate (K=512 -> 128 each)
#define ZS1 8            // split-K slices for W_ih (K=2560 -> 320 each)
#define ZS2 4            // split-K slices for W_hh (K=512 -> 128 each)
#define PS 2             // split-K slices for preds (K=512 -> 256 each)

__device__ __forceinline__ float sigmoidf_(float x) { return 1.0f / (1.0f + expf(-x)); }

// ---------------- mean over N ----------------
__global__ __launch_bounds__(256) void k_mean(const float* __restrict__ feat,
                                              float* __restrict__ mean_enc) {
    int i = blockIdx.x * 256 + threadIdx.x;
    int b = i >> 11, e = i & (E - 1);
    const float* p = feat + (size_t)b * N * E + e;
    float s = 0.f;
    for (int n = 0; n < N; ++n) s += p[(size_t)n * E];
    mean_enc[i] = s * (1.0f / (float)N);
}

// ---------------- h,c init; h written into xcat h-slot ----------------
__global__ __launch_bounds__(256) void k_init_hc(const float* __restrict__ me,
                                                 const float* __restrict__ Wh, const float* __restrict__ bh,
                                                 const float* __restrict__ Wc, const float* __restrict__ bc,
                                                 float* __restrict__ xcat, float* __restrict__ c) {
    int i = blockIdx.x * 256 + threadIdx.x;
    int b = i >> 9, d = i & (D - 1);
    const float* m = me + (size_t)b * E;
    float ha = bh[d], ca = bc[d];
    for (int e = 0; e < E; ++e) {
        float mv = m[e];
        ha += mv * Wh[(size_t)e * D + d];
        ca += mv * Wc[(size_t)e * D + d];
    }
    xcat[(size_t)b * XC + HOFF + d] = ha;
    c[i] = ca;
}

// ---------------- inp = embedding[1] into xcat ----------------
__global__ __launch_bounds__(256) void k_init_inp(const float* __restrict__ emb,
                                                  float* __restrict__ xcat) {
    int i = blockIdx.x * 256 + threadIdx.x;   // 32768
    int b = i >> 9, k = i & (EM - 1);
    xcat[(size_t)b * XC + k] = emb[EM + k];
}

// ---------------- att1 = enc @ W_enc_att ----------------
// 64 threads/block, tile 64(M)x128(N), 16x8 microtile (ratio 0.1875 -> 96 B/cyc LDS, under peak).
// Double-buffered LDS, global prefetch before compute. 784 blocks = 8 XCD chunks x 98.
__global__ __launch_bounds__(64, 2) void k_gemm_att1(const float* __restrict__ Am,
                                                     const float* __restrict__ Bm,
                                                     float* __restrict__ Cm) {
    __shared__ float As[2][16][64];    // [buf][k][m]
    __shared__ float Bs[2][16][132];   // [buf][k][n] padded (132) for conflict-free b128 writes
    int bid = blockIdx.x;                       // 784 = 8 * 98
    int s = (bid & 7) * 98 + (bid >> 3);        // XCD-chunked, bijective
    int row0 = (s >> 2) * 64, col0 = (s & 3) * 128;
    int t = threadIdx.x;
    int ty = t >> 4, tx = t & 15;               // ty: row group (*16), tx: col lane
    const float* ag_ = Am + (size_t)(row0 + t) * E;                       // A row per thread
    const float* bg_ = Bm + (size_t)(t >> 2) * AA + col0 + (t & 3) * 32;  // B: 4 thr/row
    float4 a_[4], b_[8];
    // preload k0 = 0
#pragma unroll
    for (int q = 0; q < 4; ++q) a_[q] = *(const float4*)(ag_ + q * 4);
#pragma unroll
    for (int q = 0; q < 8; ++q) b_[q] = *(const float4*)(bg_ + q * 4);
#pragma unroll
    for (int q = 0; q < 4; ++q) {
        As[0][q * 4 + 0][t] = a_[q].x; As[0][q * 4 + 1][t] = a_[q].y;
        As[0][q * 4 + 2][t] = a_[q].z; As[0][q * 4 + 3][t] = a_[q].w;
    }
#pragma unroll
    for (int q = 0; q < 8; ++q)
        *(float4*)&Bs[0][t >> 2][(t & 3) * 32 + q * 4] = b_[q];
    __syncthreads();

    float acc[16][8] = {};
    int cur = 0;
    for (int k0 = 0; k0 < E; k0 += 16) {
        bool more = (k0 + 16) < E;
        if (more) {
            const float* ap = ag_ + k0 + 16;
            const float* bp = bg_ + (size_t)(k0 + 16) * AA;
#pragma unroll
            for (int q = 0; q < 4; ++q) a_[q] = *(const float4*)(ap + q * 4);
#pragma unroll
            for (int q = 0; q < 8; ++q) b_[q] = *(const float4*)(bp + q * 4);
        }
#pragma unroll
        for (int kk = 0; kk < 16; ++kk) {
            float af[16], bf[8];
            *(float4*)&af[0]  = *(const float4*)&As[cur][kk][ty * 16];
            *(float4*)&af[4]  = *(const float4*)&As[cur][kk][ty * 16 + 4];
            *(float4*)&af[8]  = *(const float4*)&As[cur][kk][ty * 16 + 8];
            *(float4*)&af[12] = *(const float4*)&As[cur][kk][ty * 16 + 12];
#pragma unroll
            for (int j = 0; j < 8; ++j) bf[j] = Bs[cur][kk][tx + 16 * j];
#pragma unroll
            for (int i = 0; i < 16; ++i)
#pragma unroll
                for (int j = 0; j < 8; ++j)
                    acc[i][j] += af[i] * bf[j];
        }
        if (more) {
            int nb = cur ^ 1;
#pragma unroll
            for (int q = 0; q < 4; ++q) {
                As[nb][q * 4 + 0][t] = a_[q].x; As[nb][q * 4 + 1][t] = a_[q].y;
                As[nb][q * 4 + 2][t] = a_[q].z; As[nb][q * 4 + 3][t] = a_[q].w;
            }
#pragma unroll
            for (int q = 0; q < 8; ++q)
                *(float4*)&Bs[nb][t >> 2][(t & 3) * 32 + q * 4] = b_[q];
        }
        __syncthreads();
        cur ^= 1;
    }
#pragma unroll
    for (int i = 0; i < 16; ++i) {
        float* cp = &Cm[(size_t)(row0 + ty * 16 + i) * AA + col0 + tx];
#pragma unroll
        for (int j = 0; j < 8; ++j)
            cp[16 * j] = acc[i][j];
    }
}

// ---------------- att2|gate split-K: agp[sl][b][2560] ----------------
// grid (40, AGS); tiles 0-7 att2 (Wda), 8-39 gate (Wfb, +bfb in slice 0)
__global__ __launch_bounds__(256) void k_ag(const float* __restrict__ xcat,
                                            const float* __restrict__ Wda,
                                            const float* __restrict__ Wfb,
                                            const float* __restrict__ bfb,
                                            float* __restrict__ agp) {
    __shared__ float As[16][68];
    __shared__ float Bs[16][64];
    int tile = blockIdx.x, slice = blockIdx.y;
    const float* W; const float* bias = nullptr; int ldw, n0, co;
    if (tile < 8) { W = Wda; ldw = AA; n0 = tile * 64;       co = n0; }
    else          { W = Wfb; ldw = E;  n0 = (tile - 8) * 64; co = AA + n0;
                    if (slice == 0) bias = bfb; }
    float* ag = agp + (size_t)slice * B * AGW;
    int kbeg = slice * (D / AGS);
    const float* A = xcat + HOFF;
    int t = threadIdx.x;
    int tx = t & 15, ty = t >> 4;
    int arow = t >> 2, ak4 = (t & 3) * 4;
    int bk = t >> 4, bc4 = (t & 15) * 4;
    float acc[4][4] = {};
    for (int k0 = kbeg; k0 < kbeg + D / AGS; k0 += 16) {
        float4 av = *(const float4*)&A[(size_t)arow * XC + k0 + ak4];
        As[ak4 + 0][arow] = av.x; As[ak4 + 1][arow] = av.y;
        As[ak4 + 2][arow] = av.z; As[ak4 + 3][arow] = av.w;
        *(float4*)&Bs[bk][bc4] = *(const float4*)&W[(size_t)(k0 + bk) * ldw + n0 + bc4];
        __syncthreads();
#pragma unroll
        for (int kk = 0; kk < 16; ++kk) {
            float4 a4 = *(const float4*)&As[kk][ty * 4];
            float4 b4 = *(const float4*)&Bs[kk][tx * 4];
            acc[0][0] += a4.x * b4.x; acc[0][1] += a4.x * b4.y; acc[0][2] += a4.x * b4.z; acc[0][3] += a4.x * b4.w;
            acc[1][0] += a4.y * b4.x; acc[1][1] += a4.y * b4.y; acc[1][2] += a4.y * b4.z; acc[1][3] += a4.y * b4.w;
            acc[2][0] += a4.z * b4.x; acc[2][1] += a4.z * b4.y; acc[2][2] += a4.z * b4.z; acc[2][3] += a4.z * b4.w;
            acc[3][0] += a4.w * b4.x; acc[3][1] += a4.w * b4.y; acc[3][2] += a4.w * b4.z; acc[3][3] += a4.w * b4.w;
        }
        __syncthreads();
    }
#pragma unroll
    for (int i = 0; i < 4; ++i) {
        int row = ty * 4 + i;
#pragma unroll
        for (int j = 0; j < 4; ++j) {
            float v = acc[i][j];
            if (bias) v += bias[n0 + tx * 4 + j];
            ag[(size_t)row * AGW + co + tx * 4 + j] = v;
        }
    }
}

// ---------------- scores: wave per (b,n) row; sums AGS att2 partials ----------------
__global__ __launch_bounds__(256) void k_scores(const float* __restrict__ att1,
                                                const float* __restrict__ agp,
                                                const float* __restrict__ wfull,
                                                float* __restrict__ scores) {
    int wid = threadIdx.x >> 6, lane = threadIdx.x & 63;
    int bn = blockIdx.x * 4 + wid;            // 12544 rows
    int b = bn / N;
    const float* a1 = att1 + (size_t)bn * AA;
    const float* a2 = agp + (size_t)b * AGW;
    const size_t SL = (size_t)B * AGW;
    float s = 0.f;
#pragma unroll
    for (int i = 0; i < AA / 64; ++i) {
        int a = lane + i * 64;
        float v = a1[a] + a2[a] + a2[SL + a] + a2[2 * SL + a] + a2[3 * SL + a];
        s += fmaxf(v, 0.f) * wfull[a];
    }
    for (int off = 32; off; off >>= 1) s += __shfl_down(s, off);
    if (lane == 0) scores[bn] = s;
}

// ---------------- awe: in-block softmax + weighted sum + gate (sums AGS partials) ----------------
__global__ __launch_bounds__(256) void k_awe(const float* __restrict__ scores,
                                             const float* __restrict__ feat,
                                             const float* __restrict__ agp,
                                             float* __restrict__ xcat) {
    __shared__ float al[N];
    __shared__ float red[256];
    int b = blockIdx.y, ch = blockIdx.x, t = threadIdx.x;
    float v = (t < N) ? scores[b * N + t] : -INFINITY;
    red[t] = v; __syncthreads();
    for (int s = 128; s; s >>= 1) { if (t < s) red[t] = fmaxf(red[t], red[t + s]); __syncthreads(); }
    float mx = red[0]; __syncthreads();
    float e = (t < N) ? expf(v - mx) : 0.f;
    red[t] = e; __syncthreads();
    for (int s = 128; s; s >>= 1) { if (t < s) red[t] += red[t + s]; __syncthreads(); }
    float inv = 1.0f / red[0];
    if (t < N) al[t] = e * inv;
    __syncthreads();
    int e0 = ch * 256 + t;
    const float* f = feat + (size_t)b * N * E + e0;
    float s0 = 0.f;
    int n = 0;
    for (; n + 4 <= N; n += 4) {
        s0 += al[n] * f[0];
        s0 += al[n + 1] * f[E];
        s0 += al[n + 2] * f[2 * E];
        s0 += al[n + 3] * f[3 * E];
        f += (size_t)4 * E;
    }
    for (; n < N; ++n) { s0 += al[n] * f[0]; f += E; }
    const float* gp = agp + (size_t)b * AGW + AA + e0;
    const size_t SL = (size_t)B * AGW;
    float g = gp[0] + gp[SL] + gp[2 * SL] + gp[3 * SL];
    xcat[(size_t)b * XC + EM + e0] = s0 * sigmoidf_(g);
}

// ---------------- z partials: one launch, 12 slices (8 ih + 4 hh) ----------------
__global__ __launch_bounds__(256) void k_z(const float* __restrict__ xcat,
                                           const float* __restrict__ Wih,
                                           const float* __restrict__ Whh,
                                           float* __restrict__ zpart) {
    __shared__ float As[16][68];
    __shared__ float Bs[16][64];
    int slice = blockIdx.y;
    const float* A; const float* W; int kbeg, kspan;
    if (slice < ZS1) { A = xcat;        W = Wih; kbeg = slice * ((EM + E) / ZS1); kspan = (EM + E) / ZS1; }
    else             { A = xcat + HOFF; W = Whh; kbeg = (slice - ZS1) * (D / ZS2); kspan = D / ZS2; }
    float* C = zpart + (size_t)slice * B * 4 * D;
    int n0 = blockIdx.x * 64;
    int t = threadIdx.x;
    int tx = t & 15, ty = t >> 4;
    int arow = t >> 2, ak4 = (t & 3) * 4;
    int bk = t >> 4, bc4 = (t & 15) * 4;
    float acc[4][4] = {};
    for (int k0 = kbeg; k0 < kbeg + kspan; k0 += 16) {
        float4 av = *(const float4*)&A[(size_t)arow * XC + k0 + ak4];
        As[ak4 + 0][arow] = av.x; As[ak4 + 1][arow] = av.y;
        As[ak4 + 2][arow] = av.z; As[ak4 + 3][arow] = av.w;
        *(float4*)&Bs[bk][bc4] = *(const float4*)&W[(size_t)(k0 + bk) * (4 * D) + n0 + bc4];
        __syncthreads();
#pragma unroll
        for (int kk = 0; kk < 16; ++kk) {
            float4 a4 = *(const float4*)&As[kk][ty * 4];
            float4 b4 = *(const float4*)&Bs[kk][tx * 4];
            acc[0][0] += a4.x * b4.x; acc[0][1] += a4.x * b4.y; acc[0][2] += a4.x * b4.z; acc[0][3] += a4.x * b4.w;
            acc[1][0] += a4.y * b4.x; acc[1][1] += a4.y * b4.y; acc[1][2] += a4.y * b4.z; acc[1][3] += a4.y * b4.w;
            acc[2][0] += a4.z * b4.x; acc[2][1] += a4.z * b4.y; acc[2][2] += a4.z * b4.z; acc[2][3] += a4.z * b4.w;
            acc[3][0] += a4.w * b4.x; acc[3][1] += a4.w * b4.y; acc[3][2] += a4.w * b4.z; acc[3][3] += a4.w * b4.w;
        }
        __syncthreads();
    }
#pragma unroll
    for (int i = 0; i < 4; ++i) {
        int row = ty * 4 + i;
#pragma unroll
        for (int j = 0; j < 4; ++j)
            C[(size_t)row * (4 * D) + n0 + tx * 4 + j] = acc[i][j];
    }
}

// ---------------- LSTM: reduce 12 zpart slices + gates; h -> xcat h-slot ----------------
__global__ __launch_bounds__(256) void k_lstm(const float* __restrict__ zpart,
                                              const float* __restrict__ blstm,
                                              float* __restrict__ c,
                                              float* __restrict__ xcat) {
    int i = blockIdx.x * 256 + threadIdx.x;   // 32768
    int b = i >> 9, d = i & (D - 1);
    const float* zp = zpart + (size_t)b * (4 * D);
    float zi = blstm[d], zf = blstm[D + d], zg = blstm[2 * D + d], zo = blstm[3 * D + d];
#pragma unroll
    for (int s = 0; s < ZS1 + ZS2; ++s) {
        const float* p = zp + (size_t)s * B * 4 * D;
        zi += p[d]; zf += p[D + d]; zg += p[2 * D + d]; zo += p[3 * D + d];
    }
    float iv = sigmoidf_(zi), fv = sigmoidf_(zf), gv = tanhf(zg), ov = sigmoidf_(zo);
    float cn = fv * c[i] + iv * gv;
    c[i] = cn;
    xcat[(size_t)b * XC + HOFF + d] = ov * tanhf(cn);
}

// ---------------- preds split-K: predsp[sl][b][V] ----------------
__global__ __launch_bounds__(256) void k_preds(const float* __restrict__ xcat,
                                               const float* __restrict__ Wfc,
                                               const float* __restrict__ bfc,
                                               float* __restrict__ predsp) {
    __shared__ float As[16][68];
    __shared__ float Bs[16][64];
    int slice = blockIdx.y;
    int kbeg = slice * (D / PS);
    float* preds = predsp + (size_t)slice * B * V;
    const float* bias = (slice == 0) ? bfc : nullptr;
    const float* A = xcat + HOFF;
    int n0 = blockIdx.x * 64;
    int t = threadIdx.x;
    int tx = t & 15, ty = t >> 4;
    int arow = t >> 2, ak4 = (t & 3) * 4;
    int bk = t >> 4, bc4 = (t & 15) * 4;
    float acc[4][4] = {};
    for (int k0 = kbeg; k0 < kbeg + D / PS; k0 += 16) {
        float4 av = *(const float4*)&A[(size_t)arow * XC + k0 + ak4];
        As[ak4 + 0][arow] = av.x; As[ak4 + 1][arow] = av.y;
        As[ak4 + 2][arow] = av.z; As[ak4 + 3][arow] = av.w;
        int n = n0 + bc4;
        const float* wp = &Wfc[(size_t)(k0 + bk) * V];
        float4 bv;
        if (n + 3 < V) bv = *(const float4*)&wp[n];
        else {
            bv.x = (n     < V) ? wp[n]     : 0.f;
            bv.y = (n + 1 < V) ? wp[n + 1] : 0.f;
            bv.z = (n + 2 < V) ? wp[n + 2] : 0.f;
            bv.w = (n + 3 < V) ? wp[n + 3] : 0.f;
        }
        *(float4*)&Bs[bk][bc4] = bv;
        __syncthreads();
#pragma unroll
        for (int kk = 0; kk < 16; ++kk) {
            float4 a4 = *(const float4*)&As[kk][ty * 4];
            float4 b4 = *(const float4*)&Bs[kk][tx * 4];
            acc[0][0] += a4.x * b4.x; acc[0][1] += a4.x * b4.y; acc[0][2] += a4.x * b4.z; acc[0][3] += a4.x * b4.w;
            acc[1][0] += a4.y * b4.x; acc[1][1] += a4.y * b4.y; acc[1][2] += a4.y * b4.z; acc[1][3] += a4.y * b4.w;
            acc[2][0] += a4.z * b4.x; acc[2][1] += a4.z * b4.y; acc[2][2] += a4.z * b4.z; acc[2][3] += a4.z * b4.w;
            acc[3][0] += a4.w * b4.x; acc[3][1] += a4.w * b4.y; acc[3][2] += a4.w * b4.z; acc[3][3] += a4.w * b4.w;
        }
        __syncthreads();
    }
#pragma unroll
    for (int i = 0; i < 4; ++i) {
        int row = ty * 4 + i;
#pragma unroll
        for (int j = 0; j < 4; ++j) {
            int col = n0 + tx * 4 + j;
            if (col < V) {
                float v = acc[i][j];
                if (bias) v += bias[col];
                preds[(size_t)row * V + col] = v;
            }
        }
    }
}

// ---------------- argmax over V (sums PS partials) -> token + next inp ----------------
__global__ __launch_bounds__(256) void k_argmax(const float* __restrict__ predsp,
                                                const float* __restrict__ emb,
                                                float* __restrict__ xcat,
                                                int* __restrict__ out,
                                                int step) {
    __shared__ float vals[256];
    __shared__ int idxs[256];
    __shared__ int pid_sh;
    int b = blockIdx.x, t = threadIdx.x;
    const float* p0 = predsp + (size_t)b * V;
    const float* p1 = predsp + (size_t)B * V + (size_t)b * V;
    float best = -INFINITY; int bi = 0;
    for (int v = t; v < V; v += 256) {
        float pv = p0[v] + p1[v];
        if (pv > best) { best = pv; bi = v; }
    }
    vals[t] = best; idxs[t] = bi; __syncthreads();
    for (int s = 128; s; s >>= 1) {
        if (t < s) {
            float ov = vals[t + s]; int oi = idxs[t + s];
            if (ov > vals[t] || (ov == vals[t] && oi < idxs[t])) { vals[t] = ov; idxs[t] = oi; }
        }
        __syncthreads();
    }
    if (t == 0) { pid_sh = idxs[0]; out[b * TSTEPS + step] = idxs[0]; }
    __syncthreads();
    int pid = pid_sh;
    for (int k = t; k < EM; k += 256) xcat[(size_t)b * XC + k] = emb[(size_t)pid * EM + k];
}

extern "C" void kernel_launch(void* const* d_in, const int* in_sizes, int n_in,
                              void* d_out, int out_size, void* d_ws, size_t ws_size,
                              hipStream_t stream) {
    const float* feat   = (const float*)d_in[0];
    const float* emb    = (const float*)d_in[1];
    const float* Wea    = (const float*)d_in[2];
    const float* Wda    = (const float*)d_in[3];
    const float* wfull  = (const float*)d_in[4];
    const float* Wih_   = (const float*)d_in[5];
    const float* bih    = (const float*)d_in[6];
    const float* Wic    = (const float*)d_in[7];
    const float* bic    = (const float*)d_in[8];
    const float* Wfb    = (const float*)d_in[9];
    const float* bfb    = (const float*)d_in[10];
    const float* Wih    = (const float*)d_in[11];
    const float* Whh    = (const float*)d_in[12];
    const float* blstm  = (const float*)d_in[13];
    const float* Wfc    = (const float*)d_in[14];
    const float* bfc    = (const float*)d_in[15];
    int* out = (int*)d_out;

    float* ws = (float*)d_ws;
    float* att1     = ws;                              // 6,422,528
    float* mean_enc = att1 + (size_t)B * N * AA;       // 131,072
    float* c        = mean_enc + (size_t)B * E;        // 32,768
    float* agp      = c + (size_t)B * D;               // 4 x 163,840 = 655,360
    float* scores   = agp + (size_t)AGS * B * AGW;     // 12,544
    float* xcat     = scores + (size_t)B * N;          // 196,608
    float* zpart    = xcat + (size_t)B * XC;           // 12 x 131,072 = 1,572,864
    float* predsp   = zpart + (size_t)(ZS1 + ZS2) * B * 4 * D;  // 2 x 640,000
    // total ~41.2 MB

    // ---- one-time (per call) ----
    k_mean<<<(B * E) / 256, 256, 0, stream>>>(feat, mean_enc);
    k_init_hc<<<(B * D) / 256, 256, 0, stream>>>(mean_enc, Wih_, bih, Wic, bic, xcat, c);
    k_init_inp<<<(B * EM) / 256, 256, 0, stream>>>(emb, xcat);
    k_gemm_att1<<<(B * N / 64) * (AA / 128), 64, 0, stream>>>(feat, Wea, att1);

    for (int t = 0; t < TSTEPS; ++t) {
        k_ag<<<dim3(40, AGS), 256, 0, stream>>>(xcat, Wda, Wfb, bfb, agp);
        k_scores<<<(B * N) / 4, 256, 0, stream>>>(att1, agp, wfull, scores);
        k_awe<<<dim3(E / 256, B), 256, 0, stream>>>(scores, feat, agp, xcat);
        k_z<<<dim3((4 * D) / 64, ZS1 + ZS2), 256, 0, stream>>>(xcat, Wih, Whh, zpart);
        k_lstm<<<(B * D) / 256, 256, 0, stream>>>(zpart, blstm, c, xcat);
        k_preds<<<dim3((V + 63) / 64, PS), 256, 0, stream>>>(xcat, Wfc, bfc, predsp);
        k_argmax<<<B, 256, 0, stream>>>(predsp, emb, xcat, out, t);
    }
}

// Round 6
// 2252.901 us; speedup vs baseline: 2.8965x; 2.8965x over previous
//
#include <hip/hip_runtime.h>
#include <math.h>

#define B 64
#define N 196
#define E 2048
#define D 512
#define AA 512
#define EM 512
#define V 10000
#define TSTEPS 20
#define XC 3072          // xcat: [inp(512) | awe(2048) | h(512)] contiguous
#define HOFF 2560        // h slot offset in xcat
#define AGW 2560         // ag row: [att2(512) | gate(2048)]
#define AGS 4            // split-K slices for att2|gate (K=512 -> 128 each)
#define ZS1 8            // split-K slices for W_ih (K=2560 -> 320 each)
#define ZS2 4            // split-K slices for W_hh (K=512 -> 128 each)
#define PS 2             // split-K slices for preds (K=512 -> 256 each)
#define ATT1_ELEMS ((size_t)B * N * AA)   // 6422528

__device__ __forceinline__ float sigmoidf_(float x) { return 1.0f / (1.0f + expf(-x)); }

__device__ __forceinline__ float4 ldg4_guard(const float* __restrict__ wp, int n, int Nn) {
    if (n + 3 < Nn) return *(const float4*)&wp[n];
    float4 bv;
    bv.x = (n     < Nn) ? wp[n]     : 0.f;
    bv.y = (n + 1 < Nn) ? wp[n + 1] : 0.f;
    bv.z = (n + 2 < Nn) ? wp[n + 2] : 0.f;
    bv.w = (n + 3 < Nn) ? wp[n + 3] : 0.f;
    return bv;
}

// ---------------- mean over N ----------------
__global__ __launch_bounds__(256) void k_mean(const float* __restrict__ feat,
                                              float* __restrict__ mean_enc) {
    int i = blockIdx.x * 256 + threadIdx.x;
    int b = i >> 11, e = i & (E - 1);
    const float* p = feat + (size_t)b * N * E + e;
    float s = 0.f;
    for (int n = 0; n < N; ++n) s += p[(size_t)n * E];
    mean_enc[i] = s * (1.0f / (float)N);
}

// ---------------- h,c init; h written into xcat h-slot ----------------
__global__ __launch_bounds__(256) void k_init_hc(const float* __restrict__ me,
                                                 const float* __restrict__ Wh, const float* __restrict__ bh,
                                                 const float* __restrict__ Wc, const float* __restrict__ bc,
                                                 float* __restrict__ xcat, float* __restrict__ c) {
    int i = blockIdx.x * 256 + threadIdx.x;
    int b = i >> 9, d = i & (D - 1);
    const float* m = me + (size_t)b * E;
    float ha = bh[d], ca = bc[d];
    for (int e = 0; e < E; ++e) {
        float mv = m[e];
        ha += mv * Wh[(size_t)e * D + d];
        ca += mv * Wc[(size_t)e * D + d];
    }
    xcat[(size_t)b * XC + HOFF + d] = ha;
    c[i] = ca;
}

// ---------------- inp = embedding[1] into xcat ----------------
__global__ __launch_bounds__(256) void k_init_inp(const float* __restrict__ emb,
                                                  float* __restrict__ xcat) {
    int i = blockIdx.x * 256 + threadIdx.x;   // 32768
    int b = i >> 9, k = i & (EM - 1);
    xcat[(size_t)b * XC + k] = emb[EM + k];
}

// ---------------- att1 = enc @ W_enc_att : 128x128 tile, 8x8 micro, split-K 2 ----------------
// grid (392, 2). Round-4 proven body + register prefetch; slice s covers K [s*1024, s*1024+1024).
// Slice outputs contiguous (slice1 right after slice0 = att1); k_att1_red sums in place.
__global__ __launch_bounds__(256) void k_gemm_att1(const float* __restrict__ Am,
                                                   const float* __restrict__ Bm,
                                                   float* __restrict__ Cp) {
    __shared__ float As[16][128];   // [k][m]
    __shared__ float Bs[16][128];   // [k][n]
    int bid = blockIdx.x;                     // 392 = 8 XCD chunks x 49
    int swz = (bid & 7) * 49 + (bid >> 3);    // bijective
    int row0 = (swz >> 2) * 128, col0 = (swz & 3) * 128;
    int kbeg = blockIdx.y * (E / 2);
    float* Cm = Cp + (size_t)blockIdx.y * ATT1_ELEMS;
    int t = threadIdx.x;
    int lrow = t >> 1, lk8 = (t & 1) * 8;     // A staging: 2 thr/row x 8 k
    int bk = t >> 4, bc8 = (t & 15) * 8;      // B staging: 16 thr/row x 8 n
    int ty = t >> 4, tx = t & 15;
    const float* aptr = &Am[(size_t)(row0 + lrow) * E + kbeg + lk8];
    const float* bptr = &Bm[(size_t)(kbeg + bk) * AA + col0 + bc8];
    float4 pa0 = *(const float4*)aptr;
    float4 pa1 = *(const float4*)(aptr + 4);
    float4 pb0 = *(const float4*)bptr;
    float4 pb1 = *(const float4*)(bptr + 4);
    float acc[8][8] = {};
    for (int k0 = 0; k0 < E / 2; k0 += 16) {
        As[lk8 + 0][lrow] = pa0.x; As[lk8 + 1][lrow] = pa0.y;
        As[lk8 + 2][lrow] = pa0.z; As[lk8 + 3][lrow] = pa0.w;
        As[lk8 + 4][lrow] = pa1.x; As[lk8 + 5][lrow] = pa1.y;
        As[lk8 + 6][lrow] = pa1.z; As[lk8 + 7][lrow] = pa1.w;
        *(float4*)&Bs[bk][bc8]     = pb0;
        *(float4*)&Bs[bk][bc8 + 4] = pb1;
        __syncthreads();
        if (k0 + 16 < E / 2) {                // prefetch next k-tile (in flight during compute)
            const float* ap = aptr + k0 + 16;
            const float* bp = bptr + (size_t)(k0 + 16) * AA;
            pa0 = *(const float4*)ap;
            pa1 = *(const float4*)(ap + 4);
            pb0 = *(const float4*)bp;
            pb1 = *(const float4*)(bp + 4);
        }
#pragma unroll
        for (int kk = 0; kk < 16; ++kk) {
            float4 aL = *(const float4*)&As[kk][ty * 4];
            float4 aH = *(const float4*)&As[kk][64 + ty * 4];
            float4 bL = *(const float4*)&Bs[kk][tx * 4];
            float4 bH = *(const float4*)&Bs[kk][64 + tx * 4];
#define FMAROW(r, a) \
            acc[r][0] += (a) * bL.x; acc[r][1] += (a) * bL.y; acc[r][2] += (a) * bL.z; acc[r][3] += (a) * bL.w; \
            acc[r][4] += (a) * bH.x; acc[r][5] += (a) * bH.y; acc[r][6] += (a) * bH.z; acc[r][7] += (a) * bH.w;
            FMAROW(0, aL.x) FMAROW(1, aL.y) FMAROW(2, aL.z) FMAROW(3, aL.w)
            FMAROW(4, aH.x) FMAROW(5, aH.y) FMAROW(6, aH.z) FMAROW(7, aH.w)
#undef FMAROW
        }
        __syncthreads();
    }
#pragma unroll
    for (int i = 0; i < 8; ++i) {
        int row = row0 + ((i < 4) ? (ty * 4 + i) : (64 + ty * 4 + i - 4));
        float4 lo, hi;
        lo.x = acc[i][0]; lo.y = acc[i][1]; lo.z = acc[i][2]; lo.w = acc[i][3];
        hi.x = acc[i][4]; hi.y = acc[i][5]; hi.z = acc[i][6]; hi.w = acc[i][7];
        *(float4*)&Cm[(size_t)row * AA + col0 + tx * 4]      = lo;
        *(float4*)&Cm[(size_t)row * AA + col0 + 64 + tx * 4] = hi;
    }
}

// ---------------- att1 += att1 slice1 (in place, deterministic) ----------------
__global__ __launch_bounds__(256) void k_att1_red(float* __restrict__ att1) {
    size_t i = ((size_t)blockIdx.x * 256 + threadIdx.x) * 4;
    float4 a = *(float4*)&att1[i];
    float4 b = *(const float4*)&att1[i + ATT1_ELEMS];
    a.x += b.x; a.y += b.y; a.z += b.z; a.w += b.w;
    *(float4*)&att1[i] = a;
}

// ---------------- att2|gate split-K: agp[sl][b][2560] (register-prefetched) ----------------
__global__ __launch_bounds__(256) void k_ag(const float* __restrict__ xcat,
                                            const float* __restrict__ Wda,
                                            const float* __restrict__ Wfb,
                                            const float* __restrict__ bfb,
                                            float* __restrict__ agp) {
    __shared__ float As[16][68];
    __shared__ float Bs[16][64];
    int tile = blockIdx.x, slice = blockIdx.y;
    const float* W; const float* bias = nullptr; int ldw, n0, co;
    if (tile < 8) { W = Wda; ldw = AA; n0 = tile * 64;       co = n0; }
    else          { W = Wfb; ldw = E;  n0 = (tile - 8) * 64; co = AA + n0;
                    if (slice == 0) bias = bfb; }
    float* ag = agp + (size_t)slice * B * AGW;
    int kbeg = slice * (D / AGS), kend = kbeg + D / AGS;
    const float* A = xcat + HOFF;
    int t = threadIdx.x;
    int tx = t & 15, ty = t >> 4;
    int arow = t >> 2, ak4 = (t & 3) * 4;
    int bk = t >> 4, bc4 = (t & 15) * 4;
    float4 pav = *(const float4*)&A[(size_t)arow * XC + kbeg + ak4];
    float4 pbv = *(const float4*)&W[(size_t)(kbeg + bk) * ldw + n0 + bc4];
    float acc[4][4] = {};
    for (int k0 = kbeg; k0 < kend; k0 += 16) {
        As[ak4 + 0][arow] = pav.x; As[ak4 + 1][arow] = pav.y;
        As[ak4 + 2][arow] = pav.z; As[ak4 + 3][arow] = pav.w;
        *(float4*)&Bs[bk][bc4] = pbv;
        __syncthreads();
        if (k0 + 16 < kend) {
            pav = *(const float4*)&A[(size_t)arow * XC + k0 + 16 + ak4];
            pbv = *(const float4*)&W[(size_t)(k0 + 16 + bk) * ldw + n0 + bc4];
        }
#pragma unroll
        for (int kk = 0; kk < 16; ++kk) {
            float4 a4 = *(const float4*)&As[kk][ty * 4];
            float4 b4 = *(const float4*)&Bs[kk][tx * 4];
            acc[0][0] += a4.x * b4.x; acc[0][1] += a4.x * b4.y; acc[0][2] += a4.x * b4.z; acc[0][3] += a4.x * b4.w;
            acc[1][0] += a4.y * b4.x; acc[1][1] += a4.y * b4.y; acc[1][2] += a4.y * b4.z; acc[1][3] += a4.y * b4.w;
            acc[2][0] += a4.z * b4.x; acc[2][1] += a4.z * b4.y; acc[2][2] += a4.z * b4.z; acc[2][3] += a4.z * b4.w;
            acc[3][0] += a4.w * b4.x; acc[3][1] += a4.w * b4.y; acc[3][2] += a4.w * b4.z; acc[3][3] += a4.w * b4.w;
        }
        __syncthreads();
    }
#pragma unroll
    for (int i = 0; i < 4; ++i) {
        int row = ty * 4 + i;
#pragma unroll
        for (int j = 0; j < 4; ++j) {
            float v = acc[i][j];
            if (bias) v += bias[n0 + tx * 4 + j];
            ag[(size_t)row * AGW + co + tx * 4 + j] = v;
        }
    }
}

// ---------------- scores: wave per (b,n) row; sums AGS att2 partials ----------------
__global__ __launch_bounds__(256) void k_scores(const float* __restrict__ att1,
                                                const float* __restrict__ agp,
                                                const float* __restrict__ wfull,
                                                float* __restrict__ scores) {
    int wid = threadIdx.x >> 6, lane = threadIdx.x & 63;
    int bn = blockIdx.x * 4 + wid;            // 12544 rows
    int b = bn / N;
    const float* a1 = att1 + (size_t)bn * AA;
    const float* a2 = agp + (size_t)b * AGW;
    const size_t SL = (size_t)B * AGW;
    float s = 0.f;
#pragma unroll
    for (int i = 0; i < AA / 64; ++i) {
        int a = lane + i * 64;
        float v = a1[a] + a2[a] + a2[SL + a] + a2[2 * SL + a] + a2[3 * SL + a];
        s += fmaxf(v, 0.f) * wfull[a];
    }
    for (int off = 32; off; off >>= 1) s += __shfl_down(s, off);
    if (lane == 0) scores[bn] = s;
}

// ---------------- awe: in-block softmax + weighted sum + gate (sums AGS partials) ----------------
__global__ __launch_bounds__(256) void k_awe(const float* __restrict__ scores,
                                             const float* __restrict__ feat,
                                             const float* __restrict__ agp,
                                             float* __restrict__ xcat) {
    __shared__ float al[N];
    __shared__ float red[256];
    int b = blockIdx.y, ch = blockIdx.x, t = threadIdx.x;
    float v = (t < N) ? scores[b * N + t] : -INFINITY;
    red[t] = v; __syncthreads();
    for (int s = 128; s; s >>= 1) { if (t < s) red[t] = fmaxf(red[t], red[t + s]); __syncthreads(); }
    float mx = red[0]; __syncthreads();
    float e = (t < N) ? expf(v - mx) : 0.f;
    red[t] = e; __syncthreads();
    for (int s = 128; s; s >>= 1) { if (t < s) red[t] += red[t + s]; __syncthreads(); }
    float inv = 1.0f / red[0];
    if (t < N) al[t] = e * inv;
    __syncthreads();
    int e0 = ch * 256 + t;
    const float* f = feat + (size_t)b * N * E + e0;
    float s0 = 0.f;
    int n = 0;
    for (; n + 4 <= N; n += 4) {
        s0 += al[n] * f[0];
        s0 += al[n + 1] * f[E];
        s0 += al[n + 2] * f[2 * E];
        s0 += al[n + 3] * f[3 * E];
        f += (size_t)4 * E;
    }
    for (; n < N; ++n) { s0 += al[n] * f[0]; f += E; }
    const float* gp = agp + (size_t)b * AGW + AA + e0;
    const size_t SL = (size_t)B * AGW;
    float g = gp[0] + gp[SL] + gp[2 * SL] + gp[3 * SL];
    xcat[(size_t)b * XC + EM + e0] = s0 * sigmoidf_(g);
}

// ---------------- z partials: one launch, 12 slices (8 ih + 4 hh), prefetched ----------------
__global__ __launch_bounds__(256) void k_z(const float* __restrict__ xcat,
                                           const float* __restrict__ Wih,
                                           const float* __restrict__ Whh,
                                           float* __restrict__ zpart) {
    __shared__ float As[16][68];
    __shared__ float Bs[16][64];
    int slice = blockIdx.y;
    const float* A; const float* W; int kbeg, kspan;
    if (slice < ZS1) { A = xcat;        W = Wih; kbeg = slice * ((EM + E) / ZS1); kspan = (EM + E) / ZS1; }
    else             { A = xcat + HOFF; W = Whh; kbeg = (slice - ZS1) * (D / ZS2); kspan = D / ZS2; }
    int kend = kbeg + kspan;
    float* C = zpart + (size_t)slice * B * 4 * D;
    int n0 = blockIdx.x * 64;
    int t = threadIdx.x;
    int tx = t & 15, ty = t >> 4;
    int arow = t >> 2, ak4 = (t & 3) * 4;
    int bk = t >> 4, bc4 = (t & 15) * 4;
    float4 pav = *(const float4*)&A[(size_t)arow * XC + kbeg + ak4];
    float4 pbv = *(const float4*)&W[(size_t)(kbeg + bk) * (4 * D) + n0 + bc4];
    float acc[4][4] = {};
    for (int k0 = kbeg; k0 < kend; k0 += 16) {
        As[ak4 + 0][arow] = pav.x; As[ak4 + 1][arow] = pav.y;
        As[ak4 + 2][arow] = pav.z; As[ak4 + 3][arow] = pav.w;
        *(float4*)&Bs[bk][bc4] = pbv;
        __syncthreads();
        if (k0 + 16 < kend) {
            pav = *(const float4*)&A[(size_t)arow * XC + k0 + 16 + ak4];
            pbv = *(const float4*)&W[(size_t)(k0 + 16 + bk) * (4 * D) + n0 + bc4];
        }
#pragma unroll
        for (int kk = 0; kk < 16; ++kk) {
            float4 a4 = *(const float4*)&As[kk][ty * 4];
            float4 b4 = *(const float4*)&Bs[kk][tx * 4];
            acc[0][0] += a4.x * b4.x; acc[0][1] += a4.x * b4.y; acc[0][2] += a4.x * b4.z; acc[0][3] += a4.x * b4.w;
            acc[1][0] += a4.y * b4.x; acc[1][1] += a4.y * b4.y; acc[1][2] += a4.y * b4.z; acc[1][3] += a4.y * b4.w;
            acc[2][0] += a4.z * b4.x; acc[2][1] += a4.z * b4.y; acc[2][2] += a4.z * b4.z; acc[2][3] += a4.z * b4.w;
            acc[3][0] += a4.w * b4.x; acc[3][1] += a4.w * b4.y; acc[3][2] += a4.w * b4.z; acc[3][3] += a4.w * b4.w;
        }
        __syncthreads();
    }
#pragma unroll
    for (int i = 0; i < 4; ++i) {
        int row = ty * 4 + i;
#pragma unroll
        for (int j = 0; j < 4; ++j)
            C[(size_t)row * (4 * D) + n0 + tx * 4 + j] = acc[i][j];
    }
}

// ---------------- LSTM: reduce 12 zpart slices + gates; h -> xcat h-slot ----------------
__global__ __launch_bounds__(256) void k_lstm(const float* __restrict__ zpart,
                                              const float* __restrict__ blstm,
                                              float* __restrict__ c,
                                              float* __restrict__ xcat) {
    int i = blockIdx.x * 256 + threadIdx.x;   // 32768
    int b = i >> 9, d = i & (D - 1);
    const float* zp = zpart + (size_t)b * (4 * D);
    float zi = blstm[d], zf = blstm[D + d], zg = blstm[2 * D + d], zo = blstm[3 * D + d];
#pragma unroll
    for (int s = 0; s < ZS1 + ZS2; ++s) {
        const float* p = zp + (size_t)s * B * 4 * D;
        zi += p[d]; zf += p[D + d]; zg += p[2 * D + d]; zo += p[3 * D + d];
    }
    float iv = sigmoidf_(zi), fv = sigmoidf_(zf), gv = tanhf(zg), ov = sigmoidf_(zo);
    float cn = fv * c[i] + iv * gv;
    c[i] = cn;
    xcat[(size_t)b * XC + HOFF + d] = ov * tanhf(cn);
}

// ---------------- preds split-K: predsp[sl][b][V] (prefetched) ----------------
__global__ __launch_bounds__(256) void k_preds(const float* __restrict__ xcat,
                                               const float* __restrict__ Wfc,
                                               const float* __restrict__ bfc,
                                               float* __restrict__ predsp) {
    __shared__ float As[16][68];
    __shared__ float Bs[16][64];
    int slice = blockIdx.y;
    int kbeg = slice * (D / PS), kend = kbeg + D / PS;
    float* preds = predsp + (size_t)slice * B * V;
    const float* bias = (slice == 0) ? bfc : nullptr;
    const float* A = xcat + HOFF;
    int n0 = blockIdx.x * 64;
    int t = threadIdx.x;
    int tx = t & 15, ty = t >> 4;
    int arow = t >> 2, ak4 = (t & 3) * 4;
    int bk = t >> 4, bc4 = (t & 15) * 4;
    float4 pav = *(const float4*)&A[(size_t)arow * XC + kbeg + ak4];
    float4 pbv = ldg4_guard(&Wfc[(size_t)(kbeg + bk) * V], n0 + bc4, V);
    float acc[4][4] = {};
    for (int k0 = kbeg; k0 < kend; k0 += 16) {
        As[ak4 + 0][arow] = pav.x; As[ak4 + 1][arow] = pav.y;
        As[ak4 + 2][arow] = pav.z; As[ak4 + 3][arow] = pav.w;
        *(float4*)&Bs[bk][bc4] = pbv;
        __syncthreads();
        if (k0 + 16 < kend) {
            pav = *(const float4*)&A[(size_t)arow * XC + k0 + 16 + ak4];
            pbv = ldg4_guard(&Wfc[(size_t)(k0 + 16 + bk) * V], n0 + bc4, V);
        }
#pragma unroll
        for (int kk = 0; kk < 16; ++kk) {
            float4 a4 = *(const float4*)&As[kk][ty * 4];
            float4 b4 = *(const float4*)&Bs[kk][tx * 4];
            acc[0][0] += a4.x * b4.x; acc[0][1] += a4.x * b4.y; acc[0][2] += a4.x * b4.z; acc[0][3] += a4.x * b4.w;
            acc[1][0] += a4.y * b4.x; acc[1][1] += a4.y * b4.y; acc[1][2] += a4.y * b4.z; acc[1][3] += a4.y * b4.w;
            acc[2][0] += a4.z * b4.x; acc[2][1] += a4.z * b4.y; acc[2][2] += a4.z * b4.z; acc[2][3] += a4.z * b4.w;
            acc[3][0] += a4.w * b4.x; acc[3][1] += a4.w * b4.y; acc[3][2] += a4.w * b4.z; acc[3][3] += a4.w * b4.w;
        }
        __syncthreads();
    }
#pragma unroll
    for (int i = 0; i < 4; ++i) {
        int row = ty * 4 + i;
#pragma unroll
        for (int j = 0; j < 4; ++j) {
            int col = n0 + tx * 4 + j;
            if (col < V) {
                float v = acc[i][j];
                if (bias) v += bias[col];
                preds[(size_t)row * V + col] = v;
            }
        }
    }
}

// ---------------- argmax over V (sums PS partials) -> token + next inp ----------------
__global__ __launch_bounds__(256) void k_argmax(const float* __restrict__ predsp,
                                                const float* __restrict__ emb,
                                                float* __restrict__ xcat,
                                                int* __restrict__ out,
                                                int step) {
    __shared__ float vals[256];
    __shared__ int idxs[256];
    __shared__ int pid_sh;
    int b = blockIdx.x, t = threadIdx.x;
    const float* p0 = predsp + (size_t)b * V;
    const float* p1 = predsp + (size_t)B * V + (size_t)b * V;
    float best = -INFINITY; int bi = 0;
    for (int v = t; v < V; v += 256) {
        float pv = p0[v] + p1[v];
        if (pv > best) { best = pv; bi = v; }
    }
    vals[t] = best; idxs[t] = bi; __syncthreads();
    for (int s = 128; s; s >>= 1) {
        if (t < s) {
            float ov = vals[t + s]; int oi = idxs[t + s];
            if (ov > vals[t] || (ov == vals[t] && oi < idxs[t])) { vals[t] = ov; idxs[t] = oi; }
        }
        __syncthreads();
    }
    if (t == 0) { pid_sh = idxs[0]; out[b * TSTEPS + step] = idxs[0]; }
    __syncthreads();
    int pid = pid_sh;
    for (int k = t; k < EM; k += 256) xcat[(size_t)b * XC + k] = emb[(size_t)pid * EM + k];
}

extern "C" void kernel_launch(void* const* d_in, const int* in_sizes, int n_in,
                              void* d_out, int out_size, void* d_ws, size_t ws_size,
                              hipStream_t stream) {
    const float* feat   = (const float*)d_in[0];
    const float* emb    = (const float*)d_in[1];
    const float* Wea    = (const float*)d_in[2];
    const float* Wda    = (const float*)d_in[3];
    const float* wfull  = (const float*)d_in[4];
    const float* Wih_   = (const float*)d_in[5];
    const float* bih    = (const float*)d_in[6];
    const float* Wic    = (const float*)d_in[7];
    const float* bic    = (const float*)d_in[8];
    const float* Wfb    = (const float*)d_in[9];
    const float* bfb    = (const float*)d_in[10];
    const float* Wih    = (const float*)d_in[11];
    const float* Whh    = (const float*)d_in[12];
    const float* blstm  = (const float*)d_in[13];
    const float* Wfc    = (const float*)d_in[14];
    const float* bfc    = (const float*)d_in[15];
    int* out = (int*)d_out;

    float* ws = (float*)d_ws;
    float* att1     = ws;                              // slice0 (+slice1 right after): 2 x 6,422,528
    float* mean_enc = att1 + 2 * ATT1_ELEMS;           // 131,072
    float* c        = mean_enc + (size_t)B * E;        // 32,768
    float* agp      = c + (size_t)B * D;               // 655,360
    float* scores   = agp + (size_t)AGS * B * AGW;     // 12,544
    float* xcat     = scores + (size_t)B * N;          // 196,608
    float* zpart    = xcat + (size_t)B * XC;           // 1,572,864
    float* predsp   = zpart + (size_t)(ZS1 + ZS2) * B * 4 * D;  // 1,280,000
    // total ~67 MB

    // ---- one-time (per call) ----
    k_mean<<<(B * E) / 256, 256, 0, stream>>>(feat, mean_enc);
    k_init_hc<<<(B * D) / 256, 256, 0, stream>>>(mean_enc, Wih_, bih, Wic, bic, xcat, c);
    k_init_inp<<<(B * EM) / 256, 256, 0, stream>>>(emb, xcat);
    k_gemm_att1<<<dim3((B * N / 128) * (AA / 128), 2), 256, 0, stream>>>(feat, Wea, att1);
    k_att1_red<<<ATT1_ELEMS / 1024, 256, 0, stream>>>(att1);

    for (int t = 0; t < TSTEPS; ++t) {
        k_ag<<<dim3(40, AGS), 256, 0, stream>>>(xcat, Wda, Wfb, bfb, agp);
        k_scores<<<(B * N) / 4, 256, 0, stream>>>(att1, agp, wfull, scores);
        k_awe<<<dim3(E / 256, B), 256, 0, stream>>>(scores, feat, agp, xcat);
        k_z<<<dim3((4 * D) / 64, ZS1 + ZS2), 256, 0, stream>>>(xcat, Wih, Whh, zpart);
        k_lstm<<<(B * D) / 256, 256, 0, stream>>>(zpart, blstm, c, xcat);
        k_preds<<<dim3((V + 63) / 64, PS), 256, 0, stream>>>(xcat, Wfc, bfc, predsp);
        k_argmax<<<B, 256, 0, stream>>>(predsp, emb, xcat, out, t);
    }
}